// Round 1
// baseline (42.830 us; speedup 1.0000x reference)
//
#include <hip/hip_runtime.h>
#include <math.h>

// Problem constants (fixed by setup_inputs):
// B=8, PN=8 -> BP=64 blocks; PL=511 -> L=512; NV=2; H=8; DK=DV=32; D=256;
// DM=512; HID=4*D=1024.
namespace {
constexpr int L   = 512;
constexpr int H   = 8;
constexpr int DK  = 32;
constexpr int D   = 256;
constexpr int DM  = 512;
constexpr int HID = 1024;
constexpr int NT  = 512;   // threads per block
constexpr float INV_SQRT_DK = 0.17677669529663687f;  // 1/sqrt(32)
// ln(1000)/16 for theta_j = 1000^(-j/16) = exp(-j*ln(1000)/16)
constexpr float LN1000_D16 = 0.4317347049836665f;

__global__ __launch_bounds__(NT, 2)
void iblock_fused(const float* __restrict__ x,
                  const float* __restrict__ t,
                  const int*   __restrict__ mask,
                  const float* __restrict__ emb,
                  const float* __restrict__ Wq,
                  const float* __restrict__ Wk,
                  const float* __restrict__ Wv,
                  const float* __restrict__ Wo,
                  const float* __restrict__ ln_g,
                  const float* __restrict__ ln_b,
                  const float* __restrict__ W1,
                  const float* __restrict__ b1,
                  const float* __restrict__ W2,
                  const float* __restrict__ b2,
                  float* __restrict__ out) {
  const int bp   = blockIdx.x;   // b*PN + pn
  const int tid  = threadIdx.x;  // 0..511
  const int lane = tid & 63;
  const int wid  = tid >> 6;     // 0..7

  __shared__ float xx0s[L], xx1s[L];          // input (with emb token at l=0)
  __shared__ float wqs[2*D], wks[2*D], wvs[2*D];
  __shared__ float qls[D];                    // RoPE'd, pre-scaled query row
  __shared__ float red[24];                   // cross-wave reduction scratch
  __shared__ float lastv[D];                  // attention output (emb query)
  __shared__ float hids[HID];                 // FFN hidden
  __shared__ float part[NT];                  // FFN second-layer partials
  __shared__ float ynv[D];                    // layernorm output
  __shared__ int   m0s;

  // ---- stage xx and the tiny projection weights into LDS ----
  {
    float v0, v1;
    if (tid == 0) { v0 = emb[0]; v1 = emb[1]; }
    else {
      const float* xp = x + (size_t)(bp * 511 + (tid - 1)) * 2;
      v0 = xp[0]; v1 = xp[1];
    }
    xx0s[tid] = v0; xx1s[tid] = v1;
  }
  wqs[tid] = Wq[tid]; wks[tid] = Wk[tid]; wvs[tid] = Wv[tid];  // 2*D == NT
  if (tid == 0) m0s = mask[bp * L];
  __syncthreads();

  // ---- per-thread RoPE tables for key position l = tid ----
  float cj[16], sj[16];
  const float tl = t[bp * L + tid];
  const int   ml = mask[bp * L + tid];
  #pragma unroll
  for (int j = 0; j < 16; ++j) {
    float theta = expf(-(float)j * LN1000_D16);
    sincosf(tl * theta, &sj[j], &cj[j]);
  }

  // ---- query row (position 0), RoPE'd and pre-scaled by 1/sqrt(DK) ----
  if (tid < 128) {            // one rope pair per thread: 8 heads x 16 pairs
    int h = tid >> 4, j = tid & 15;
    int col = h * DK + 2 * j;
    float re = xx0s[0] * wqs[col]     + xx1s[0] * wqs[D + col];
    float im = xx0s[0] * wqs[col + 1] + xx1s[0] * wqs[D + col + 1];
    float theta = expf(-(float)j * LN1000_D16);
    float s0, c0;
    sincosf(t[bp * L] * theta, &s0, &c0);
    qls[col]     = (re * c0 - im * s0) * INV_SQRT_DK;
    qls[col + 1] = (re * s0 + im * c0) * INV_SQRT_DK;
  }
  __syncthreads();

  const float xl0 = xx0s[tid], xl1 = xx1s[tid];
  const bool masked = (m0s * ml) == 0;

  // ---- attention: one key position per thread, per head ----
  for (int h = 0; h < H; ++h) {
    float sc = 0.f;
    #pragma unroll
    for (int j = 0; j < 16; ++j) {
      int col = h * DK + 2 * j;
      float xr  = xl0 * wks[col]     + xl1 * wks[D + col];
      float xi  = xl0 * wks[col + 1] + xl1 * wks[D + col + 1];
      float kre = xr * cj[j] - xi * sj[j];
      float kim = xr * sj[j] + xi * cj[j];
      sc += qls[col] * kre + qls[col + 1] * kim;
    }
    if (masked) sc = -1e9f;

    // block max
    float mx = sc;
    #pragma unroll
    for (int o = 32; o; o >>= 1) mx = fmaxf(mx, __shfl_xor(mx, o));
    if (lane == 0) red[wid] = mx;
    __syncthreads();
    mx = red[0];
    #pragma unroll
    for (int w = 1; w < 8; ++w) mx = fmaxf(mx, red[w]);

    // exp + fused triple reduction: sum(e), sum(e*xx0), sum(e*xx1)
    float e = expf(sc - mx);
    float se = e, s0a = e * xl0, s1a = e * xl1;
    #pragma unroll
    for (int o = 32; o; o >>= 1) {
      se  += __shfl_xor(se, o);
      s0a += __shfl_xor(s0a, o);
      s1a += __shfl_xor(s1a, o);
    }
    __syncthreads();  // everyone done reading red (max) before overwrite
    if (lane == 0) { red[wid] = se; red[8 + wid] = s0a; red[16 + wid] = s1a; }
    __syncthreads();
    se = 0.f; s0a = 0.f; s1a = 0.f;
    #pragma unroll
    for (int w = 0; w < 8; ++w) {
      se += red[w]; s0a += red[8 + w]; s1a += red[16 + w];
    }

    // attn @ V  ==  ((attn @ xx) @ Wv) since NV=2 and V has no RoPE
    if (tid < DK) {
      int col = h * DK + tid;
      lastv[col] = (s0a * wvs[col] + s1a * wvs[D + col]) / se;
    }
    __syncthreads();  // red reusable next head; lastv visible later
  }

  // ---- FFN layer 1: hid[j] = relu(b1[j] + last . W1[:,j]) ----
  #pragma unroll
  for (int r = 0; r < 2; ++r) {
    int j = tid + r * NT;
    float acc = b1[j];
    for (int i = 0; i < D; ++i) acc = fmaf(lastv[i], W1[i * HID + j], acc);
    hids[j] = fmaxf(acc, 0.f);
  }
  __syncthreads();

  // ---- FFN layer 2 (split over j): part[tid] over half the hidden dim ----
  {
    int i  = tid & 255;
    int jb = (tid >> 8) * 512;
    float acc = 0.f;
    for (int j = 0; j < 512; ++j)
      acc = fmaf(hids[jb + j], W2[(size_t)(jb + j) * D + i], acc);
    part[tid] = acc;
  }
  __syncthreads();

  // ---- residual + layernorm ----
  float yv = 0.f;
  if (tid < D) yv = lastv[tid] + b2[tid] + part[tid] + part[tid + 256];
  float ssum = yv, ssq = yv * yv;
  #pragma unroll
  for (int o = 32; o; o >>= 1) {
    ssum += __shfl_xor(ssum, o);
    ssq  += __shfl_xor(ssq, o);
  }
  if (lane == 0) { red[wid] = ssum; red[8 + wid] = ssq; }
  __syncthreads();
  ssum = 0.f; ssq = 0.f;
  #pragma unroll
  for (int w = 0; w < 8; ++w) { ssum += red[w]; ssq += red[8 + w]; }
  const float mu   = ssum / (float)D;
  const float var  = ssq / (float)D - mu * mu;
  const float rstd = rsqrtf(var + 1e-5f);
  if (tid < D) ynv[tid] = (yv - mu) * rstd * ln_g[tid] + ln_b[tid];
  __syncthreads();

  // ---- final projection: out[bp, tid] = yn . Wo[:, tid] ----
  {
    float acc = 0.f;
    for (int i = 0; i < D; ++i) acc = fmaf(ynv[i], Wo[(size_t)i * DM + tid], acc);
    out[(size_t)bp * DM + tid] = acc;
  }
}
}  // namespace

extern "C" void kernel_launch(void* const* d_in, const int* in_sizes, int n_in,
                              void* d_out, int out_size, void* d_ws, size_t ws_size,
                              hipStream_t stream) {
  const float* x    = (const float*)d_in[0];
  const float* t    = (const float*)d_in[1];
  const int*   mask = (const int*)  d_in[2];
  const float* emb  = (const float*)d_in[3];
  const float* Wq   = (const float*)d_in[4];
  const float* Wk   = (const float*)d_in[5];
  const float* Wv   = (const float*)d_in[6];
  const float* Wo   = (const float*)d_in[7];
  const float* lng  = (const float*)d_in[8];
  const float* lnb  = (const float*)d_in[9];
  const float* W1   = (const float*)d_in[10];
  const float* b1   = (const float*)d_in[11];
  const float* W2   = (const float*)d_in[12];
  const float* b2   = (const float*)d_in[13];
  float* out = (float*)d_out;

  iblock_fused<<<64, NT, 0, stream>>>(x, t, mask, emb, Wq, Wk, Wv, Wo,
                                      lng, lnb, W1, b1, W2, b2, out);
}

// Round 2
// 40.345 us; speedup vs baseline: 1.0616x; 1.0616x over previous
//
#include <hip/hip_runtime.h>
#include <math.h>

// B=8, PN=8 -> BP=64; PL=511 -> L=512; NV=2; H=8; DK=DV=32; D=256; DM=512; HID=1024.
namespace {
constexpr int L   = 512;
constexpr int D   = 256;
constexpr int DM  = 512;
constexpr int HID = 1024;
constexpr float INV_SQRT_DK = 0.17677669529663687f;  // 1/sqrt(32)
constexpr float LN1000_D16  = 0.4317347049836665f;   // ln(1000)/16

// ---------------- K1: attention, one block per (bp, head) ----------------
__global__ __launch_bounds__(512, 2)
void k_attn(const float* __restrict__ x, const float* __restrict__ t,
            const int* __restrict__ mask, const float* __restrict__ emb,
            const float* __restrict__ Wq, const float* __restrict__ Wk,
            const float* __restrict__ Wv, float* __restrict__ last) {
  const int bp = blockIdx.x >> 3, h = blockIdx.x & 7;
  const int tid = threadIdx.x, lane = tid & 63, wid = tid >> 6;

  __shared__ float xx0s[L], xx1s[L];
  __shared__ float wq0[32], wq1[32], wk0[32], wk1[32], wv0[32], wv1[32];
  __shared__ float qh[32];
  __shared__ float red[24];
  __shared__ int   m0s;

  if (tid == 0) { xx0s[0] = emb[0]; xx1s[0] = emb[1]; m0s = mask[bp * L]; }
  else {
    float2 v = reinterpret_cast<const float2*>(x)[bp * (L - 1) + tid - 1];
    xx0s[tid] = v.x; xx1s[tid] = v.y;
  }
  if (tid < 32) {
    wq0[tid] = Wq[h * 32 + tid];       wq1[tid] = Wq[256 + h * 32 + tid];
    wk0[tid] = Wk[h * 32 + tid];       wk1[tid] = Wk[256 + h * 32 + tid];
    wv0[tid] = Wv[h * 32 + tid];       wv1[tid] = Wv[256 + h * 32 + tid];
  }

  // per-thread RoPE tables for key position l = tid (thetas fold to literals)
  const float tl = t[bp * L + tid];
  const int   ml = mask[bp * L + tid];
  float cj[16], sj[16];
  #pragma unroll
  for (int j = 0; j < 16; ++j) {
    const float theta = expf(-(float)j * LN1000_D16);  // compile-time folded
    sincosf(tl * theta, &sj[j], &cj[j]);
  }
  __syncthreads();

  if (tid < 16) {  // query row (pos 0) for this head, RoPE'd + pre-scaled
    const float t0 = t[bp * L];
    const float re = xx0s[0] * wq0[2 * tid]     + xx1s[0] * wq1[2 * tid];
    const float im = xx0s[0] * wq0[2 * tid + 1] + xx1s[0] * wq1[2 * tid + 1];
    float s0, c0;
    sincosf(t0 * expf(-(float)tid * LN1000_D16), &s0, &c0);
    qh[2 * tid]     = (re * c0 - im * s0) * INV_SQRT_DK;
    qh[2 * tid + 1] = (re * s0 + im * c0) * INV_SQRT_DK;
  }
  __syncthreads();

  const float xl0 = xx0s[tid], xl1 = xx1s[tid];
  float sc = 0.f;
  #pragma unroll
  for (int j = 0; j < 16; ++j) {
    const int c = 2 * j;
    const float xr  = xl0 * wk0[c]     + xl1 * wk1[c];
    const float xi  = xl0 * wk0[c + 1] + xl1 * wk1[c + 1];
    const float kre = xr * cj[j] - xi * sj[j];
    const float kim = xr * sj[j] + xi * cj[j];
    sc += qh[c] * kre + qh[c + 1] * kim;
  }
  if ((m0s * ml) == 0) sc = -1e9f;

  // block max over 512
  float mx = sc;
  #pragma unroll
  for (int o = 32; o; o >>= 1) mx = fmaxf(mx, __shfl_xor(mx, o));
  if (lane == 0) red[wid] = mx;
  __syncthreads();
  mx = red[0];
  #pragma unroll
  for (int w = 1; w < 8; ++w) mx = fmaxf(mx, red[w]);

  // exp + fused triple reduction: sum(e), sum(e*xx0), sum(e*xx1)
  const float e = expf(sc - mx);
  float se = e, s0a = e * xl0, s1a = e * xl1;
  #pragma unroll
  for (int o = 32; o; o >>= 1) {
    se  += __shfl_xor(se, o);
    s0a += __shfl_xor(s0a, o);
    s1a += __shfl_xor(s1a, o);
  }
  __syncthreads();  // everyone done reading red(max) before overwrite
  if (lane == 0) { red[wid] = se; red[8 + wid] = s0a; red[16 + wid] = s1a; }
  __syncthreads();
  se = 0.f; s0a = 0.f; s1a = 0.f;
  #pragma unroll
  for (int w = 0; w < 8; ++w) { se += red[w]; s0a += red[8 + w]; s1a += red[16 + w]; }

  // attn@V == ((attn@xx)@Wv), since NV=2 and V carries no RoPE
  if (tid < 32) last[bp * 256 + h * 32 + tid] = (s0a * wv0[tid] + s1a * wv1[tid]) / se;
}

// ---------------- K2: hid = relu(last @ W1 + b1) ----------------
// grid 64 = 16 N-tiles(64) x 4 M-tiles(16); 256 threads
__global__ __launch_bounds__(256, 4)
void k_ffn1(const float* __restrict__ last, const float* __restrict__ W1,
            const float* __restrict__ b1, float* __restrict__ hid) {
  const int nt = blockIdx.x & 15, mt = blockIdx.x >> 4;
  const int tid = threadIdx.x;
  __shared__ float ls[16][257];
  #pragma unroll
  for (int q = 0; q < 16; ++q) {
    const int idx = tid + q * 256;
    ls[idx >> 8][idx & 255] = last[(mt * 16 + (idx >> 8)) * 256 + (idx & 255)];
  }
  __syncthreads();
  const int j = nt * 64 + (tid & 63);
  const int rg = tid >> 6;  // 0..3 -> rows rg*4 .. rg*4+3
  float a0 = b1[j], a1 = a0, a2 = a0, a3 = a0;
  #pragma unroll 8
  for (int i = 0; i < 256; ++i) {
    const float w = W1[i * HID + j];
    a0 = fmaf(ls[rg * 4 + 0][i], w, a0);
    a1 = fmaf(ls[rg * 4 + 1][i], w, a1);
    a2 = fmaf(ls[rg * 4 + 2][i], w, a2);
    a3 = fmaf(ls[rg * 4 + 3][i], w, a3);
  }
  const int rb = mt * 16 + rg * 4;
  hid[(rb + 0) * HID + j] = fmaxf(a0, 0.f);
  hid[(rb + 1) * HID + j] = fmaxf(a1, 0.f);
  hid[(rb + 2) * HID + j] = fmaxf(a2, 0.f);
  hid[(rb + 3) * HID + j] = fmaxf(a3, 0.f);
}

// ---------------- K3: partial[kt] = hid[:,ktslice] @ W2[ktslice,:] ----------------
// grid 64 = 16 kt x 4 nt; 256 threads; 4x4 register tile per thread
__global__ __launch_bounds__(256, 4)
void k_ffn2(const float* __restrict__ hid, const float* __restrict__ W2,
            float* __restrict__ partial) {
  const int nt = blockIdx.x & 3, kt = blockIdx.x >> 2;
  const int tid = threadIdx.x;
  __shared__ float hs[64][65];
  __shared__ float ws2[64][64];
  #pragma unroll
  for (int q = 0; q < 16; ++q) {
    const int idx = tid + q * 256;
    const int r = idx >> 6, c = idx & 63;
    hs[r][c]  = hid[r * HID + kt * 64 + c];
    ws2[r][c] = W2[(kt * 64 + r) * D + nt * 64 + c];
  }
  __syncthreads();
  const int cg = tid & 15, rg = tid >> 4;
  float acc[4][4] = {};
  for (int k = 0; k < 64; ++k) {
    const float w0 = ws2[k][cg * 4 + 0], w1 = ws2[k][cg * 4 + 1];
    const float w2v = ws2[k][cg * 4 + 2], w3 = ws2[k][cg * 4 + 3];
    #pragma unroll
    for (int r = 0; r < 4; ++r) {
      const float hv = hs[rg * 4 + r][k];
      acc[r][0] = fmaf(hv, w0, acc[r][0]);
      acc[r][1] = fmaf(hv, w1, acc[r][1]);
      acc[r][2] = fmaf(hv, w2v, acc[r][2]);
      acc[r][3] = fmaf(hv, w3, acc[r][3]);
    }
  }
  #pragma unroll
  for (int r = 0; r < 4; ++r) {
    const int bp_ = rg * 4 + r;
    float4 v = make_float4(acc[r][0], acc[r][1], acc[r][2], acc[r][3]);
    *reinterpret_cast<float4*>(&partial[(kt * 64 + bp_) * 256 + nt * 64 + cg * 4]) = v;
  }
}

// ---------------- K4: y = last + b2 + sum_kt partial; layernorm -> yn ----------------
__global__ __launch_bounds__(256, 4)
void k_ln(const float* __restrict__ last, const float* __restrict__ partial,
          const float* __restrict__ b2, const float* __restrict__ ln_g,
          const float* __restrict__ ln_b, float* __restrict__ yn) {
  const int bp = blockIdx.x, tid = threadIdx.x;
  const int lane = tid & 63, wid = tid >> 6;
  __shared__ float red[8];
  float y = last[bp * 256 + tid] + b2[tid];
  #pragma unroll
  for (int kt = 0; kt < 16; ++kt) y += partial[(kt * 64 + bp) * 256 + tid];
  float ssum = y, ssq = y * y;
  #pragma unroll
  for (int o = 32; o; o >>= 1) { ssum += __shfl_xor(ssum, o); ssq += __shfl_xor(ssq, o); }
  if (lane == 0) { red[wid] = ssum; red[4 + wid] = ssq; }
  __syncthreads();
  ssum = 0.f; ssq = 0.f;
  #pragma unroll
  for (int w = 0; w < 4; ++w) { ssum += red[w]; ssq += red[4 + w]; }
  const float mu   = ssum / (float)D;
  const float var  = ssq / (float)D - mu * mu;
  const float rstd = rsqrtf(var + 1e-5f);
  yn[bp * 256 + tid] = (y - mu) * rstd * ln_g[tid] + ln_b[tid];
}

// ---------------- K5: out = yn @ Wo ----------------
// grid 64 = 8 mt(8 rows) x 8 nt(64 cols); 256 threads
__global__ __launch_bounds__(256, 4)
void k_out(const float* __restrict__ yn, const float* __restrict__ Wo,
           float* __restrict__ out) {
  const int nt = blockIdx.x & 7, mt = blockIdx.x >> 3;
  const int tid = threadIdx.x;
  __shared__ float ys[8][257];
  #pragma unroll
  for (int q = 0; q < 8; ++q) {
    const int idx = tid + q * 256;
    ys[idx >> 8][idx & 255] = yn[(mt * 8 + (idx >> 8)) * 256 + (idx & 255)];
  }
  __syncthreads();
  const int j = nt * 64 + (tid & 63), rg = tid >> 6;
  float a0 = 0.f, a1 = 0.f;
  #pragma unroll 8
  for (int i = 0; i < 256; ++i) {
    const float w = Wo[i * DM + j];
    a0 = fmaf(ys[rg * 2 + 0][i], w, a0);
    a1 = fmaf(ys[rg * 2 + 1][i], w, a1);
  }
  out[(mt * 8 + rg * 2 + 0) * DM + j] = a0;
  out[(mt * 8 + rg * 2 + 1) * DM + j] = a1;
}
}  // namespace

extern "C" void kernel_launch(void* const* d_in, const int* in_sizes, int n_in,
                              void* d_out, int out_size, void* d_ws, size_t ws_size,
                              hipStream_t stream) {
  const float* x    = (const float*)d_in[0];
  const float* t    = (const float*)d_in[1];
  const int*   mask = (const int*)  d_in[2];
  const float* emb  = (const float*)d_in[3];
  const float* Wq   = (const float*)d_in[4];
  const float* Wk   = (const float*)d_in[5];
  const float* Wv   = (const float*)d_in[6];
  const float* Wo   = (const float*)d_in[7];
  const float* lng  = (const float*)d_in[8];
  const float* lnb  = (const float*)d_in[9];
  const float* W1   = (const float*)d_in[10];
  const float* b1   = (const float*)d_in[11];
  const float* W2   = (const float*)d_in[12];
  const float* b2   = (const float*)d_in[13];
  float* out = (float*)d_out;

  float* ws      = (float*)d_ws;
  float* last    = ws;                    // 64*256
  float* hid     = ws + 16384;            // 64*1024
  float* partial = ws + 16384 + 65536;    // 16*64*256
  float* yn      = ws + 16384 + 65536 + 262144;  // 64*256

  k_attn<<<512, 512, 0, stream>>>(x, t, mask, emb, Wq, Wk, Wv, last);
  k_ffn1<<<64, 256, 0, stream>>>(last, W1, b1, hid);
  k_ffn2<<<64, 256, 0, stream>>>(hid, W2, partial);
  k_ln  <<<64, 256, 0, stream>>>(last, partial, b2, lng, lnb, yn);
  k_out <<<64, 256, 0, stream>>>(yn, Wo, out);
}